// Round 8
// baseline (17.486 us; speedup 1.0000x reference)
//
#include <hip/hip_runtime.h>

// StructuredPerceptron: B=32, S=2048, T=512
// loss = sum_b max(pred_score_b - gold_score_b, 0)
// score_b = sum_{s<L} unary[b,s,tag[s]] + sum_{1<=s<L} binary[tag[s-1],tag[s]]
// L = sum_s mask[b,s]
//
// Discriminating experiment (R7 ~= R4 despite 8x CU spread):
// keep the proven R4 structure (32 blocks, single node, free 32-way counter
// sync, predicated gathers) but use 1024-thread blocks -> 16 waves/CU
// issuing scattered gathers concurrently (vs 4), 2 positions/thread (vs 8).
// If gather service is wave-concurrency-limited this cuts the gather phase
// 2-4x; if dur stays ~11.1 we are at the graph-replay floor.

#define BB 32
#define SS 2048
#define TT 512
#define NT 1024
#define NW (NT / 64)   // 16 waves

__device__ int sp_counter = 0;  // invariant: ==0 whenever no kernel in flight

__global__ __launch_bounds__(NT) void sp_fused_kernel(
    const float* __restrict__ unary,
    const float* __restrict__ binary,
    const int*   __restrict__ tags,
    const int*   __restrict__ pred,
    const int*   __restrict__ mask,
    float*       __restrict__ ws,
    float*       __restrict__ out)
{
    const int b    = blockIdx.x;
    const int tid  = threadIdx.x;
    const int wave = tid >> 6;

    __shared__ int   s_ipart[NW];
    __shared__ float s_part[2 * NW];
    __shared__ int   s_len;

    // ---- 1. prefetch coalesced streams (2 positions/thread) ----
    int tg[2], tp[2], tg0[2], tp0[2];
    #pragma unroll
    for (int k = 0; k < 2; ++k) {
        const int s    = tid + k * NT;
        const int base = b * SS + s;
        tg[k]  = tags[base];
        tp[k]  = pred[base];
        tg0[k] = (s >= 1) ? tags[base - 1] : 0;
        tp0[k] = (s >= 1) ? pred[base - 1] : 0;
    }
    // mask: one int2 contiguous per thread
    const int2 mv = *reinterpret_cast<const int2*>(&mask[b * SS + tid * 2]);

    // ---- 2. seq_len reduce (overlaps in-flight tag/pred loads) ----
    int m = mv.x + mv.y;
    #pragma unroll
    for (int off = 32; off > 0; off >>= 1) m += __shfl_down(m, off);
    if ((tid & 63) == 0) s_ipart[wave] = m;
    __syncthreads();
    if (tid == 0) {
        int t = 0;
        #pragma unroll
        for (int w = 0; w < NW; ++w) t += s_ipart[w];
        s_len = t;
    }
    __syncthreads();
    const int L = s_len;

    // ---- 3. predicated scattered gathers (16 waves in flight) ----
    float g = 0.f, p = 0.f;
    #pragma unroll
    for (int k = 0; k < 2; ++k) {
        const int s    = tid + k * NT;
        const int base = b * SS + s;
        if (s < L) {
            g += unary[base * TT + tg[k]];
            p += unary[base * TT + tp[k]];
            if (s >= 1) {
                g += binary[tg0[k] * TT + tg[k]];
                p += binary[tp0[k] * TT + tp[k]];
            }
        }
    }

    // ---- 4. block reduce ----
    #pragma unroll
    for (int off = 32; off > 0; off >>= 1) {
        g += __shfl_down(g, off);
        p += __shfl_down(p, off);
    }
    if ((tid & 63) == 0) { s_part[wave * 2] = g; s_part[wave * 2 + 1] = p; }
    __syncthreads();

    // ---- 5. publish + last-block finish ----
    if (tid == 0) {
        float G = 0.f, P = 0.f;
        #pragma unroll
        for (int w = 0; w < NW; ++w) { G += s_part[2 * w]; P += s_part[2 * w + 1]; }
        ws[2 * b]     = G;
        ws[2 * b + 1] = P;
        __threadfence();                        // publish ws before arrival
        const int old = atomicAdd(&sp_counter, 1);
        if (old == BB - 1) {                    // last block: finish
            __threadfence();                    // acquire all ws writes
            float total = 0.f;
            for (int i = 0; i < BB; ++i) {      // fixed order -> deterministic
                const float Gi = ws[2 * i];
                const float Pi = ws[2 * i + 1];
                total += fmaxf(Pi - Gi, 0.f);
            }
            out[0] = total;
            atomicExch(&sp_counter, 0);         // restore invariant for replay
        }
    }
}

extern "C" void kernel_launch(void* const* d_in, const int* in_sizes, int n_in,
                              void* d_out, int out_size, void* d_ws, size_t ws_size,
                              hipStream_t stream) {
    const float* unary  = (const float*)d_in[0];
    const float* binary = (const float*)d_in[1];
    const int*   tags   = (const int*)d_in[2];
    const int*   pred   = (const int*)d_in[3];
    const int*   mask   = (const int*)d_in[4];
    float* ws  = (float*)d_ws;
    float* out = (float*)d_out;

    sp_fused_kernel<<<BB, NT, 0, stream>>>(unary, binary, tags, pred, mask, ws, out);
}

// Round 9
// 12.296 us; speedup vs baseline: 1.4220x; 1.4220x over previous
//
#include <hip/hip_runtime.h>

// StructuredPerceptron: B=32, S=2048, T=512
// loss = sum_b max(pred_score_b - gold_score_b, 0)
// score_b = sum_{s<L} unary[b,s,tag[s]] + sum_{1<=s<L} binary[tag[s-1],tag[s]]
// L = sum_s mask[b,s]
//
// Best-known structure = R4 (32 blocks x 256 thr, single node, predicated
// gathers, coalesced tag prefetch). R8 proved wave-concurrency does NOT
// help (per-CU request throughput limit); R5/R6 proved extra gathers and
// wide grids hurt. This version removes the last removable serial stage:
// L is computed per-wave (redundant full-row int4 mask reduce + shfl_xor
// butterfly) -> no __syncthreads, no LDS round-trip before the gathers;
// each wave starts its scattered gathers as soon as ITS reduce is done.

#define BB 32
#define SS 2048
#define TT 512

__device__ int sp_counter = 0;  // invariant: ==0 whenever no kernel in flight

__global__ __launch_bounds__(256) void sp_fused_kernel(
    const float* __restrict__ unary,
    const float* __restrict__ binary,
    const int*   __restrict__ tags,
    const int*   __restrict__ pred,
    const int*   __restrict__ mask,
    float*       __restrict__ ws,
    float*       __restrict__ out)
{
    const int b    = blockIdx.x;
    const int tid  = threadIdx.x;
    const int wave = tid >> 6;
    const int lane = tid & 63;

    __shared__ float s_part[8];

    // ---- 1. coalesced tag/pred prefetch (8 positions/thread, stride 256) ----
    int tg[8], tp[8], tg0[8], tp0[8];
    #pragma unroll
    for (int k = 0; k < 8; ++k) {
        const int s    = tid + k * 256;
        const int base = b * SS + s;
        tg[k]  = tags[base];
        tp[k]  = pred[base];
        tg0[k] = (s >= 1) ? tags[base - 1] : 0;
        tp0[k] = (s >= 1) ? pred[base - 1] : 0;
    }

    // ---- 2. per-wave redundant mask reduce (no barriers, no LDS) ----
    // Each wave reads the whole 8KB row as int4 (64 lanes x 8 x 16B),
    // butterfly-reduces so every lane holds L.
    const int4* mrow = reinterpret_cast<const int4*>(&mask[b * SS]);
    int msum = 0;
    #pragma unroll
    for (int j = 0; j < 8; ++j) {
        const int4 v = mrow[lane + j * 64];
        msum += v.x + v.y + v.z + v.w;
    }
    #pragma unroll
    for (int off = 32; off > 0; off >>= 1) msum += __shfl_xor(msum, off);
    const int L = msum;

    // ---- 3. predicated scattered gathers (issue as soon as wave has L) ----
    float g = 0.f, p = 0.f;
    #pragma unroll
    for (int k = 0; k < 8; ++k) {
        const int s    = tid + k * 256;
        const int base = b * SS + s;
        if (s < L) {
            g += unary[base * TT + tg[k]];
            p += unary[base * TT + tp[k]];
            if (s >= 1) {
                g += binary[tg0[k] * TT + tg[k]];
                p += binary[tp0[k] * TT + tp[k]];
            }
        }
    }

    // ---- 4. block reduce (single barrier) ----
    #pragma unroll
    for (int off = 32; off > 0; off >>= 1) {
        g += __shfl_down(g, off);
        p += __shfl_down(p, off);
    }
    if (lane == 0) { s_part[wave * 2] = g; s_part[wave * 2 + 1] = p; }
    __syncthreads();

    // ---- 5. publish + last-block finish ----
    if (tid == 0) {
        const float G = s_part[0] + s_part[2] + s_part[4] + s_part[6];
        const float P = s_part[1] + s_part[3] + s_part[5] + s_part[7];
        ws[2 * b]     = G;
        ws[2 * b + 1] = P;
        __threadfence();                        // publish ws before arrival
        const int old = atomicAdd(&sp_counter, 1);
        if (old == BB - 1) {                    // last block: finish
            __threadfence();                    // acquire all ws writes
            float total = 0.f;
            for (int i = 0; i < BB; ++i) {      // fixed order -> deterministic
                const float Gi = ws[2 * i];
                const float Pi = ws[2 * i + 1];
                total += fmaxf(Pi - Gi, 0.f);
            }
            out[0] = total;
            atomicExch(&sp_counter, 0);         // restore invariant for replay
        }
    }
}

extern "C" void kernel_launch(void* const* d_in, const int* in_sizes, int n_in,
                              void* d_out, int out_size, void* d_ws, size_t ws_size,
                              hipStream_t stream) {
    const float* unary  = (const float*)d_in[0];
    const float* binary = (const float*)d_in[1];
    const int*   tags   = (const int*)d_in[2];
    const int*   pred   = (const int*)d_in[3];
    const int*   mask   = (const int*)d_in[4];
    float* ws  = (float*)d_ws;
    float* out = (float*)d_out;

    sp_fused_kernel<<<BB, 256, 0, stream>>>(unary, binary, tags, pred, mask, ws, out);
}